// Round 2
// baseline (2856.259 us; speedup 1.0000x reference)
//
#include <hip/hip_runtime.h>
#include <hip/hip_bf16.h>

#define NPIX 16384   // 128*128
#define BATCH 4
#define DIM 256
#define HEADS 8
#define HD 32
#define CHQKV 768
#define HID 680
#define HID2 1360

__global__ void zero_kernel(float* __restrict__ p, int n) {
    int i = blockIdx.x * blockDim.x + threadIdx.x;
    if (i < n) p[i] = 0.f;
}

// ---------------- LN stats: per-pixel mean / rstd over C=256 channels (one image) ----------------
__global__ void ln_stats(const float* __restrict__ x, float* __restrict__ mu,
                         float* __restrict__ rstd) {
    // grid 256 blocks, 256 threads = 64 pixels x 4 channel-groups
    int px = threadIdx.x & 63;
    int cg = threadIdx.x >> 6;
    int p = blockIdx.x * 64 + px;           // pixel 0..16383
    const float* base = x + p;
    float s = 0.f, s2 = 0.f;
    for (int c = cg * 64; c < cg * 64 + 64; ++c) {
        float v = base[(size_t)c * NPIX];
        s += v; s2 += v * v;
    }
    __shared__ float Ss[256], Ss2[256];
    Ss[threadIdx.x] = s; Ss2[threadIdx.x] = s2;
    __syncthreads();
    if (cg == 0) {
        float ts = 0.f, ts2 = 0.f;
        #pragma unroll
        for (int g = 0; g < 4; ++g) { ts += Ss[g * 64 + px]; ts2 += Ss2[g * 64 + px]; }
        float m = ts * (1.0f / DIM);
        float var = ts2 * (1.0f / DIM) - m * m;
        mu[p] = m;
        rstd[p] = rsqrtf(var + 1e-5f);
    }
}

// ---------------- fp32 tiled GEMM (one image): Out(M,NPIX) = Wm(M,K) @ X(K,NPIX) ----------------
// optional LN applied to X on load; optional residual added in epilogue. In-place res==Out is safe.
template <bool LN, bool RES>
__global__ void gemm128(const float* __restrict__ Wm, const float* __restrict__ X,
                        const float* __restrict__ bias,
                        const float* __restrict__ mu, const float* __restrict__ rstd,
                        const float* __restrict__ lnw, const float* __restrict__ lnb,
                        const float* __restrict__ res, float* __restrict__ Out,
                        int M, int K) {
    __shared__ float As[8][128];
    __shared__ float Bs[8][128];
    int tid = threadIdx.x;
    int m0 = blockIdx.y * 128;
    int n0 = blockIdx.x * 128;             // pixel start within image
    int tx = tid & 15, ty = tid >> 4;

    float acc[8][8];
    #pragma unroll
    for (int i = 0; i < 8; ++i)
        #pragma unroll
        for (int j = 0; j < 8; ++j) acc[i][j] = 0.f;

    int ar = tid >> 1;            // A row 0..127
    int ak = (tid & 1) * 4;       // A k offset 0 or 4
    int bk = tid >> 5;            // B k 0..7
    int bn = (tid & 31) * 4;      // B col offset

    for (int k0 = 0; k0 < K; k0 += 8) {
        float4 a4;
        if (m0 + ar < M) a4 = *(const float4*)&Wm[(size_t)(m0 + ar) * K + k0 + ak];
        else a4 = make_float4(0.f, 0.f, 0.f, 0.f);
        float4 b4 = *(const float4*)&X[(size_t)(k0 + bk) * NPIX + n0 + bn];
        if (LN) {
            float4 m4 = *(const float4*)&mu[n0 + bn];
            float4 r4 = *(const float4*)&rstd[n0 + bn];
            float wk = lnw[k0 + bk], bb = lnb[k0 + bk];
            b4.x = (b4.x - m4.x) * r4.x * wk + bb;
            b4.y = (b4.y - m4.y) * r4.y * wk + bb;
            b4.z = (b4.z - m4.z) * r4.z * wk + bb;
            b4.w = (b4.w - m4.w) * r4.w * wk + bb;
        }
        __syncthreads();
        As[ak + 0][ar] = a4.x;
        As[ak + 1][ar] = a4.y;
        As[ak + 2][ar] = a4.z;
        As[ak + 3][ar] = a4.w;
        *(float4*)&Bs[bk][bn] = b4;
        __syncthreads();
        #pragma unroll
        for (int kk = 0; kk < 8; ++kk) {
            float a[8], bb2[8];
            *(float4*)&a[0] = *(float4*)&As[kk][ty * 8];
            *(float4*)&a[4] = *(float4*)&As[kk][ty * 8 + 4];
            *(float4*)&bb2[0] = *(float4*)&Bs[kk][tx * 8];
            *(float4*)&bb2[4] = *(float4*)&Bs[kk][tx * 8 + 4];
            #pragma unroll
            for (int i = 0; i < 8; ++i)
                #pragma unroll
                for (int j = 0; j < 8; ++j) acc[i][j] += a[i] * bb2[j];
        }
    }
    // epilogue
    #pragma unroll
    for (int i = 0; i < 8; ++i) {
        int m = m0 + ty * 8 + i;
        if (m >= M) continue;
        float bi = bias[m];
        size_t rowoff = (size_t)m * NPIX + n0;
        #pragma unroll
        for (int j = 0; j < 8; j += 4) {
            float4 o;
            o.x = acc[i][j + 0] + bi;
            o.y = acc[i][j + 1] + bi;
            o.z = acc[i][j + 2] + bi;
            o.w = acc[i][j + 3] + bi;
            if (RES) {
                float4 r = *(const float4*)&res[rowoff + tx * 8 + j];
                o.x += r.x; o.y += r.y; o.z += r.z; o.w += r.w;
            }
            *(float4*)&Out[rowoff + tx * 8 + j] = o;
        }
    }
}

// ---------------- depthwise 3x3 (SAME) for qkv (one image), fused sum-of-squares for q,k ----------------
__global__ void dwconv_sumsq(const float* __restrict__ in, const float* __restrict__ w9,
                             const float* __restrict__ bias, float* __restrict__ out,
                             float* __restrict__ ssq, float* __restrict__ ssk) {
    // grid = 768*64 (row pairs); block 256 = 2 rows x 128 cols
    int bid = blockIdx.x;
    int rp = bid & 63;
    int ch = bid >> 6;              // 0..767
    int tid = threadIdx.x;
    int wq = tid & 127;
    int h = rp * 2 + (tid >> 7);
    const float* src = in + (size_t)ch * NPIX;
    float wgt[9];
    #pragma unroll
    for (int i = 0; i < 9; ++i) wgt[i] = w9[ch * 9 + i];
    float acc = bias[ch];
    #pragma unroll
    for (int dy = -1; dy <= 1; ++dy) {
        int hh = h + dy;
        if (hh < 0 || hh > 127) continue;
        #pragma unroll
        for (int dx = -1; dx <= 1; ++dx) {
            int ww = wq + dx;
            if (ww < 0 || ww > 127) continue;
            acc += wgt[(dy + 1) * 3 + (dx + 1)] * src[hh * 128 + ww];
        }
    }
    out[(size_t)ch * NPIX + h * 128 + wq] = acc;

    __shared__ float red[256];
    if (ch < 512) {   // q or k channel -> accumulate sum of squares
        red[tid] = acc * acc;
        __syncthreads();
        for (int st = 128; st > 0; st >>= 1) {
            if (tid < st) red[tid] += red[tid + st];
            __syncthreads();
        }
        if (tid == 0) {
            float* dst = (ch < DIM) ? &ssq[ch] : &ssk[ch - DIM];
            atomicAdd(dst, red[0]);
        }
    }
}

// ---------------- Gram: G[h,c,d] = sum_n q[c,n]*k[d,n] (raw, unnormalized), one image ----------------
__global__ void gram_kernel(const float* __restrict__ qkv, float* __restrict__ G) {
    // grid (8 heads, 32 pixel-chunks of 512), block 256
    int hH = blockIdx.x;
    int n0 = blockIdx.y * 512;
    __shared__ float qs[32][68];
    __shared__ float ks[32][68];
    int tid = threadIdx.x;
    int c = tid >> 3;             // 0..31
    int lo = (tid & 7) * 8;       // 0..56
    int dbase = tid & 7;
    const float* qbase = qkv + ((size_t)hH * HD + c) * NPIX;
    const float* kbase = qbase + (size_t)DIM * NPIX;
    float acc[4] = {0.f, 0.f, 0.f, 0.f};
    for (int t0 = 0; t0 < 512; t0 += 64) {
        __syncthreads();
        *(float4*)&qs[c][lo]     = *(const float4*)&qbase[n0 + t0 + lo];
        *(float4*)&qs[c][lo + 4] = *(const float4*)&qbase[n0 + t0 + lo + 4];
        *(float4*)&ks[c][lo]     = *(const float4*)&kbase[n0 + t0 + lo];
        *(float4*)&ks[c][lo + 4] = *(const float4*)&kbase[n0 + t0 + lo + 4];
        __syncthreads();
        for (int t = 0; t < 64; ++t) {
            float qv = qs[c][t];
            #pragma unroll
            for (int j = 0; j < 4; ++j) acc[j] += qv * ks[dbase + 8 * j][t];
        }
    }
    float* Gb = G + hH * 1024 + c * 32;
    #pragma unroll
    for (int j = 0; j < 4; ++j) atomicAdd(&Gb[dbase + 8 * j], acc[j]);
}

// ---------------- softmax over d with l2-norm scaling and temperature (one image) ----------------
__global__ void attn_softmax(const float* __restrict__ G, const float* __restrict__ ssq,
                             const float* __restrict__ ssk, const float* __restrict__ temp,
                             float* __restrict__ A) {
    int hH = blockIdx.x;            // 0..7
    int tid = threadIdx.x;          // 1024 threads: c=tid>>5, d=tid&31
    int c = tid >> 5, d = tid & 31;
    float nq = fmaxf(sqrtf(ssq[hH * HD + c]), 1e-12f);
    float nk = fmaxf(sqrtf(ssk[hH * HD + d]), 1e-12f);
    float v = G[hH * 1024 + c * 32 + d] / (nq * nk) * temp[hH];
    float m = v;
    #pragma unroll
    for (int s = 1; s < 32; s <<= 1) m = fmaxf(m, __shfl_xor(m, s, 32));
    float e = expf(v - m);
    float ssum = e;
    #pragma unroll
    for (int s = 1; s < 32; s <<= 1) ssum += __shfl_xor(ssum, s, 32);
    A[hH * 1024 + c * 32 + d] = e / ssum;
}

// ---------------- PV: out[h*32+c, n] = sum_d A[c,d] * v[d,n] (one image) ----------------
__global__ void pv_kernel(const float* __restrict__ A, const float* __restrict__ qkv,
                          float* __restrict__ out) {
    // grid (8 heads, 64 pixel-chunks of 256), block 256
    int hH = blockIdx.x;
    int n = blockIdx.y * 256 + threadIdx.x;
    __shared__ float As[1024];
    for (int i = threadIdx.x; i < 1024; i += 256) As[i] = A[hH * 1024 + i];
    __syncthreads();
    const float* vbase = qkv + ((size_t)(512 + hH * HD)) * NPIX + n;
    float vv[32];
    #pragma unroll
    for (int d = 0; d < 32; ++d) vv[d] = vbase[(size_t)d * NPIX];
    float* obase = out + ((size_t)hH * HD) * NPIX + n;
    for (int cc = 0; cc < 32; ++cc) {
        float acc = 0.f;
        #pragma unroll
        for (int d = 0; d < 32; ++d) acc += As[cc * 32 + d] * vv[d];
        obase[(size_t)cc * NPIX] = acc;
    }
}

// ---------------- FFN depthwise 3x3 on both halves + gating y1*gelu(y2) (one image) ----------------
__global__ void dwgate(const float* __restrict__ in, const float* __restrict__ w9,
                       const float* __restrict__ bias, float* __restrict__ out) {
    // grid = 680*64; block 256 = 2 rows x 128 cols
    int bid = blockIdx.x;
    int rp = bid & 63;
    int cg = bid >> 6;              // 0..679
    int tid = threadIdx.x;
    int wq = tid & 127;
    int h = rp * 2 + (tid >> 7);
    float w1[9], w2[9];
    #pragma unroll
    for (int i = 0; i < 9; ++i) { w1[i] = w9[cg * 9 + i]; w2[i] = w9[(cg + HID) * 9 + i]; }
    const float* s1 = in + (size_t)cg * NPIX;
    const float* s2 = s1 + (size_t)HID * NPIX;
    float a1 = bias[cg], a2 = bias[cg + HID];
    #pragma unroll
    for (int dy = -1; dy <= 1; ++dy) {
        int hh = h + dy;
        if (hh < 0 || hh > 127) continue;
        #pragma unroll
        for (int dx = -1; dx <= 1; ++dx) {
            int ww = wq + dx;
            if (ww < 0 || ww > 127) continue;
            int o = hh * 128 + ww;
            int wi = (dy + 1) * 3 + (dx + 1);
            a1 += w1[wi] * s1[o];
            a2 += w2[wi] * s2[o];
        }
    }
    float g = 0.5f * a2 * (1.0f + erff(a2 * 0.70710678118654752f));
    out[(size_t)cg * NPIX + h * 128 + wq] = a1 * g;
}

extern "C" void kernel_launch(void* const* d_in, const int* in_sizes, int n_in,
                              void* d_out, int out_size, void* d_ws, size_t ws_size,
                              hipStream_t stream) {
    const float* x        = (const float*)d_in[0];
    const float* n1w      = (const float*)d_in[1];
    const float* n1b      = (const float*)d_in[2];
    const float* temp     = (const float*)d_in[3];
    const float* qkv_w    = (const float*)d_in[4];
    const float* qkv_b    = (const float*)d_in[5];
    const float* qkv_dw_w = (const float*)d_in[6];
    const float* qkv_dw_b = (const float*)d_in[7];
    const float* po_w     = (const float*)d_in[8];
    const float* po_b     = (const float*)d_in[9];
    const float* n2w      = (const float*)d_in[10];
    const float* n2b      = (const float*)d_in[11];
    const float* pin_w    = (const float*)d_in[12];
    const float* pin_b    = (const float*)d_in[13];
    const float* dw_w     = (const float*)d_in[14];
    const float* dw_b     = (const float*)d_in[15];
    const float* pout_w   = (const float*)d_in[16];
    const float* pout_b   = (const float*)d_in[17];
    float* out = (float*)d_out;

    // Per-image workspace (~181 MB total)
    float* R0   = (float*)d_ws;                     // 768*16384 = 12,582,912 f
    float* R1   = R0 + 12582912ull;                 // 768*16384
    float* R2   = R1 + 12582912ull;                 // 1360*16384 = 22,282,240 f
    float* muB  = R2 + 22282240ull;                 // 16384
    float* rstdB= muB + 16384;                      // 16384
    float* G    = rstdB + 16384;                    // 8192 (8 heads x 32 x 32)
    float* ssq  = G + 8192;                         // 256
    float* ssk  = ssq + 256;                        // 256
    float* attnA= ssk + 256;                        // 8192

    for (int b = 0; b < BATCH; ++b) {
        const float* xb = x + (size_t)b * DIM * NPIX;
        float* outb = out + (size_t)b * DIM * NPIX;

        // ---- attention branch ----
        ln_stats<<<256, 256, 0, stream>>>(xb, muB, rstdB);
        gemm128<true, false><<<dim3(128, 6), 256, 0, stream>>>(
            qkv_w, xb, qkv_b, muB, rstdB, n1w, n1b, nullptr, R0, CHQKV, DIM);
        zero_kernel<<<9, 1024, 0, stream>>>(G, 8192 + 512);   // G, ssq, ssk contiguous
        dwconv_sumsq<<<CHQKV * 64, 256, 0, stream>>>(R0, qkv_dw_w, qkv_dw_b, R1, ssq, ssk);
        gram_kernel<<<dim3(8, 32), 256, 0, stream>>>(R1, G);
        attn_softmax<<<8, 1024, 0, stream>>>(G, ssq, ssk, temp, attnA);
        pv_kernel<<<dim3(8, 64), 256, 0, stream>>>(attnA, R1, R0);
        gemm128<false, true><<<dim3(128, 2), 256, 0, stream>>>(
            po_w, R0, po_b, nullptr, nullptr, nullptr, nullptr, xb, outb, DIM, DIM);

        // ---- FFN branch ----
        ln_stats<<<256, 256, 0, stream>>>(outb, muB, rstdB);
        gemm128<true, false><<<dim3(128, 11), 256, 0, stream>>>(
            pin_w, outb, pin_b, muB, rstdB, n2w, n2b, nullptr, R2, HID2, DIM);
        dwgate<<<HID * 64, 256, 0, stream>>>(R2, dw_w, dw_b, R0);
        gemm128<false, true><<<dim3(128, 2), 256, 0, stream>>>(
            pout_w, R0, pout_b, nullptr, nullptr, nullptr, nullptr, outb, outb, DIM, HID);
    }
}

// Round 3
// 2050.772 us; speedup vs baseline: 1.3928x; 1.3928x over previous
//
#include <hip/hip_runtime.h>
#include <hip/hip_bf16.h>

#define NPIX 16384   // 128*128
#define BATCH 4
#define DIM 256
#define HEADS 8
#define HD 32
#define CHQKV 768
#define HID 680
#define HID2 1360

typedef __attribute__((ext_vector_type(8))) short short8v;
typedef __attribute__((ext_vector_type(4))) float float4v;

__device__ __forceinline__ ushort bf_hi(float v) {
    unsigned u = __float_as_uint(v);
    u += 0x7fffu + ((u >> 16) & 1u);          // RNE to bf16
    return (ushort)(u >> 16);
}
__device__ __forceinline__ float bf_tof(ushort h) {
    return __uint_as_float(((unsigned)h) << 16);
}
__device__ __forceinline__ void bf_split(float v, ushort &h, ushort &l) {
    h = bf_hi(v);
    l = bf_hi(v - bf_tof(h));
}

__global__ void zero_kernel(float* __restrict__ p, int n) {
    int i = blockIdx.x * blockDim.x + threadIdx.x;
    if (i < n) p[i] = 0.f;
}

// ---- one-time: split all 4 weight matrices into bf16 hi/lo planes ([m][k] layout) ----
__global__ void convert_weights(const float* __restrict__ qkv_w, const float* __restrict__ po_w,
                                const float* __restrict__ pin_w, const float* __restrict__ pout_w,
                                ushort* __restrict__ qH, ushort* __restrict__ qL,
                                ushort* __restrict__ oH, ushort* __restrict__ oL,
                                ushort* __restrict__ iH, ushort* __restrict__ iL,
                                ushort* __restrict__ uH, ushort* __restrict__ uL) {
    int i = blockIdx.x * 256 + threadIdx.x;
    const float* s; ushort *dh, *dl; int off;
    if (i < 196608)      { s = qkv_w;  dh = qH; dl = qL; off = i; }
    else if (i < 262144) { s = po_w;   dh = oH; dl = oL; off = i - 196608; }
    else if (i < 610304) { s = pin_w;  dh = iH; dl = iL; off = i - 262144; }
    else if (i < 784384) { s = pout_w; dh = uH; dl = uL; off = i - 610304; }
    else return;
    ushort h, l; bf_split(s[off], h, l);
    dh[off] = h; dl[off] = l;
}

// ---- fused LN stats + apply, writing k-pair-interleaved bf16 hi/lo planes ----
// XH/XL word layout: word[(c>>1)*NPIX + p] = {lo16: ch c even, hi16: ch c+1}
__global__ void ln_fused(const float* __restrict__ x, const float* __restrict__ lw,
                         const float* __restrict__ lb, uint* __restrict__ XH,
                         uint* __restrict__ XL) {
    __shared__ float Ss[256], Ss2[256], muS[64], rsS[64], wS[256], bS[256];
    int t = threadIdx.x, px = t & 63, cg = t >> 6, c0 = cg * 64;
    int p = blockIdx.x * 64 + px;
    wS[t] = lw[t]; bS[t] = lb[t];
    float v[64]; float s = 0.f, s2 = 0.f;
    #pragma unroll
    for (int j = 0; j < 64; ++j) {
        v[j] = x[(size_t)(c0 + j) * NPIX + p];
        s += v[j]; s2 += v[j] * v[j];
    }
    Ss[t] = s; Ss2[t] = s2;
    __syncthreads();
    if (t < 64) {
        float ts = Ss[t] + Ss[t + 64] + Ss[t + 128] + Ss[t + 192];
        float t2 = Ss2[t] + Ss2[t + 64] + Ss2[t + 128] + Ss2[t + 192];
        float m = ts * (1.0f / DIM);
        float var = t2 * (1.0f / DIM) - m * m;
        muS[t] = m; rsS[t] = rsqrtf(var + 1e-5f);
    }
    __syncthreads();
    float m = muS[px], r = rsS[px];
    #pragma unroll
    for (int j = 0; j < 64; j += 2) {
        float a = (v[j] - m) * r * wS[c0 + j] + bS[c0 + j];
        float b2 = (v[j + 1] - m) * r * wS[c0 + j + 1] + bS[c0 + j + 1];
        ushort h0, l0, h1, l1; bf_split(a, h0, l0); bf_split(b2, h1, l1);
        size_t w = (size_t)((c0 + j) >> 1) * NPIX + p;
        XH[w] = (uint)h0 | ((uint)h1 << 16);
        XL[w] = (uint)l0 | ((uint)l1 << 16);
    }
}

// ---- MFMA GEMM: Out(M,NPIX) = W(M,K) @ X(K,NPIX), 3-term bf16 hi/lo ----
// A (weights) read direct from global bf16 planes; B from paired global planes via LDS.
template <bool RES>
__global__ void gemm_mfma(const ushort* __restrict__ WH, const ushort* __restrict__ WL,
                          const uint* __restrict__ BpH, const uint* __restrict__ BpL,
                          const float* __restrict__ bias, const float* __restrict__ res,
                          float* __restrict__ Out, int M, int K, int ksteps) {
    __shared__ uint BhL[128 * 20];   // [n][20 u32] = [n][k-pair], 80B row stride
    __shared__ uint BlL[128 * 20];
    __shared__ float biasS[128];
    const int N = NPIX;
    int tid = threadIdx.x;
    int m0 = blockIdx.y * 128;
    int n0 = blockIdx.x * 128;
    int l = tid & 63;
    int wid = tid >> 6;
    int wr = wid >> 1, wc = wid & 1;
    int lr = l & 15, lk = l >> 4;
    int kp = tid & 15;
    int nn8 = (tid >> 4) * 8;

    if (tid < 128) biasS[tid] = (m0 + tid < M) ? bias[m0 + tid] : 0.f;

    float4v acc[4][4];
    #pragma unroll
    for (int i = 0; i < 4; ++i)
        #pragma unroll
        for (int j = 0; j < 4; ++j) acc[i][j] = (float4v)0.f;

    const int Kh = K >> 1;
    for (int ks = 0; ks < ksteps; ++ks) {
        int k0 = ks * 32;
        int kpg = (k0 >> 1) + kp;
        bool kin = kpg < Kh;
        int kpc = kin ? kpg : (Kh - 1);
        const uint* ph = &BpH[(size_t)kpc * N + n0 + nn8];
        const uint* pl = &BpL[(size_t)kpc * N + n0 + nn8];
        uint4 h0 = *(const uint4*)ph;
        uint4 h1 = *(const uint4*)(ph + 4);
        uint4 g0 = *(const uint4*)pl;
        uint4 g1 = *(const uint4*)(pl + 4);
        if (!kin) {
            h0 = make_uint4(0, 0, 0, 0); h1 = h0; g0 = h0; g1 = h0;
        }
        __syncthreads();
        int r0 = nn8 * 20 + kp;
        BhL[r0      ] = h0.x; BhL[r0 + 20] = h0.y; BhL[r0 + 40] = h0.z; BhL[r0 + 60] = h0.w;
        BhL[r0 + 80 ] = h1.x; BhL[r0 +100] = h1.y; BhL[r0 +120] = h1.z; BhL[r0 +140] = h1.w;
        BlL[r0      ] = g0.x; BlL[r0 + 20] = g0.y; BlL[r0 + 40] = g0.z; BlL[r0 + 60] = g0.w;
        BlL[r0 + 80 ] = g1.x; BlL[r0 +100] = g1.y; BlL[r0 +120] = g1.z; BlL[r0 +140] = g1.w;
        __syncthreads();

        short8v ah[4], al[4], bh[4], bl[4];
        int kk = k0 + lk * 8;
        bool kok = (kk + 7) < K;
        int kc = kok ? kk : 0;
        #pragma unroll
        for (int mi = 0; mi < 4; ++mi) {
            int arow = m0 + wr * 64 + mi * 16 + lr;
            bool ok = (arow < M) && kok;
            int arc = arow < M ? arow : (M - 1);
            short8v th = *(const short8v*)&WH[(size_t)arc * K + kc];
            short8v tl = *(const short8v*)&WL[(size_t)arc * K + kc];
            short8v z = (short8v)0;
            ah[mi] = ok ? th : z;
            al[mi] = ok ? tl : z;
        }
        #pragma unroll
        for (int ni = 0; ni < 4; ++ni) {
            int brow = wc * 64 + ni * 16 + lr;
            bh[ni] = *(const short8v*)&BhL[brow * 20 + lk * 4];
            bl[ni] = *(const short8v*)&BlL[brow * 20 + lk * 4];
        }
        #pragma unroll
        for (int mi = 0; mi < 4; ++mi)
            #pragma unroll
            for (int ni = 0; ni < 4; ++ni) {
                acc[mi][ni] = __builtin_amdgcn_mfma_f32_16x16x32_bf16(ah[mi], bh[ni], acc[mi][ni], 0, 0, 0);
                acc[mi][ni] = __builtin_amdgcn_mfma_f32_16x16x32_bf16(ah[mi], bl[ni], acc[mi][ni], 0, 0, 0);
                acc[mi][ni] = __builtin_amdgcn_mfma_f32_16x16x32_bf16(al[mi], bh[ni], acc[mi][ni], 0, 0, 0);
            }
    }

    int lr4 = lk * 4;
    #pragma unroll
    for (int mi = 0; mi < 4; ++mi) {
        #pragma unroll
        for (int ni = 0; ni < 4; ++ni) {
            int rloc = wr * 64 + mi * 16 + lr4;
            int col = n0 + wc * 64 + ni * 16 + lr;
            #pragma unroll
            for (int r = 0; r < 4; ++r) {
                int row = m0 + rloc + r;
                if (row < M) {
                    float v = acc[mi][ni][r] + biasS[rloc + r];
                    size_t o = (size_t)row * N + col;
                    if (RES) v += res[o];
                    Out[o] = v;
                }
            }
        }
    }
}

// ---- depthwise 3x3 (SAME) for qkv, fused sum-of-squares for q,k ----
__global__ void dwconv_sumsq(const float* __restrict__ in, const float* __restrict__ w9,
                             const float* __restrict__ bias, float* __restrict__ out,
                             float* __restrict__ ssq, float* __restrict__ ssk) {
    int bid = blockIdx.x;
    int rp = bid & 63;
    int ch = bid >> 6;              // 0..767
    int tid = threadIdx.x;
    int wq = tid & 127;
    int h = rp * 2 + (tid >> 7);
    const float* src = in + (size_t)ch * NPIX;
    float wgt[9];
    #pragma unroll
    for (int i = 0; i < 9; ++i) wgt[i] = w9[ch * 9 + i];
    float acc = bias[ch];
    #pragma unroll
    for (int dy = -1; dy <= 1; ++dy) {
        int hh = h + dy;
        if (hh < 0 || hh > 127) continue;
        #pragma unroll
        for (int dx = -1; dx <= 1; ++dx) {
            int ww = wq + dx;
            if (ww < 0 || ww > 127) continue;
            acc += wgt[(dy + 1) * 3 + (dx + 1)] * src[hh * 128 + ww];
        }
    }
    out[(size_t)ch * NPIX + h * 128 + wq] = acc;

    __shared__ float red[256];
    if (ch < 512) {
        red[tid] = acc * acc;
        __syncthreads();
        for (int st = 128; st > 0; st >>= 1) {
            if (tid < st) red[tid] += red[tid + st];
            __syncthreads();
        }
        if (tid == 0) {
            float* dst = (ch < DIM) ? &ssq[ch] : &ssk[ch - DIM];
            atomicAdd(dst, red[0]);
        }
    }
}

// ---- Gram: G[h,c,d] = sum_n q[c,n]*k[d,n] ----
__global__ void gram_kernel(const float* __restrict__ qkv, float* __restrict__ G) {
    int hH = blockIdx.x;
    int n0 = blockIdx.y * 512;
    __shared__ float qs[32][68];
    __shared__ float ks[32][68];
    int tid = threadIdx.x;
    int c = tid >> 3;
    int lo = (tid & 7) * 8;
    int dbase = tid & 7;
    const float* qbase = qkv + ((size_t)hH * HD + c) * NPIX;
    const float* kbase = qbase + (size_t)DIM * NPIX;
    float acc[4] = {0.f, 0.f, 0.f, 0.f};
    for (int t0 = 0; t0 < 512; t0 += 64) {
        __syncthreads();
        *(float4*)&qs[c][lo]     = *(const float4*)&qbase[n0 + t0 + lo];
        *(float4*)&qs[c][lo + 4] = *(const float4*)&qbase[n0 + t0 + lo + 4];
        *(float4*)&ks[c][lo]     = *(const float4*)&kbase[n0 + t0 + lo];
        *(float4*)&ks[c][lo + 4] = *(const float4*)&kbase[n0 + t0 + lo + 4];
        __syncthreads();
        for (int t = 0; t < 64; ++t) {
            float qv = qs[c][t];
            #pragma unroll
            for (int j = 0; j < 4; ++j) acc[j] += qv * ks[dbase + 8 * j][t];
        }
    }
    float* Gb = G + hH * 1024 + c * 32;
    #pragma unroll
    for (int j = 0; j < 4; ++j) atomicAdd(&Gb[dbase + 8 * j], acc[j]);
}

// ---- softmax over d with l2-norm scaling and temperature ----
__global__ void attn_softmax(const float* __restrict__ G, const float* __restrict__ ssq,
                             const float* __restrict__ ssk, const float* __restrict__ temp,
                             float* __restrict__ A) {
    int hH = blockIdx.x;
    int tid = threadIdx.x;
    int c = tid >> 5, d = tid & 31;
    float nq = fmaxf(sqrtf(ssq[hH * HD + c]), 1e-12f);
    float nk = fmaxf(sqrtf(ssk[hH * HD + d]), 1e-12f);
    float v = G[hH * 1024 + c * 32 + d] / (nq * nk) * temp[hH];
    float m = v;
    #pragma unroll
    for (int s = 1; s < 32; s <<= 1) m = fmaxf(m, __shfl_xor(m, s, 32));
    float e = expf(v - m);
    float ssum = e;
    #pragma unroll
    for (int s = 1; s < 32; s <<= 1) ssum += __shfl_xor(ssum, s, 32);
    A[hH * 1024 + c * 32 + d] = e / ssum;
}

// ---- PV: writes paired bf16 hi/lo ----
__global__ void pv_kernel(const float* __restrict__ A, const float* __restrict__ qkv,
                          uint* __restrict__ VH, uint* __restrict__ VL) {
    int hH = blockIdx.x;
    int n = blockIdx.y * 256 + threadIdx.x;
    __shared__ float As[1024];
    for (int i = threadIdx.x; i < 1024; i += 256) As[i] = A[hH * 1024 + i];
    __syncthreads();
    const float* vbase = qkv + ((size_t)(512 + hH * HD)) * NPIX + n;
    float vv[32];
    #pragma unroll
    for (int d = 0; d < 32; ++d) vv[d] = vbase[(size_t)d * NPIX];
    #pragma unroll
    for (int cc = 0; cc < 32; cc += 2) {
        float a0 = 0.f, a1 = 0.f;
        #pragma unroll
        for (int d = 0; d < 32; ++d) {
            a0 += As[cc * 32 + d] * vv[d];
            a1 += As[cc * 32 + 32 + d] * vv[d];
        }
        ushort h0, l0, h1, l1; bf_split(a0, h0, l0); bf_split(a1, h1, l1);
        size_t w = (size_t)((hH * HD + cc) >> 1) * NPIX + n;
        VH[w] = (uint)h0 | ((uint)h1 << 16);
        VL[w] = (uint)l0 | ((uint)l1 << 16);
    }
}

// ---- FFN depthwise 3x3 + gating, 2 output channels per block, paired bf16 out ----
__global__ void dwgate(const float* __restrict__ in, const float* __restrict__ w9,
                       const float* __restrict__ bias, uint* __restrict__ GH,
                       uint* __restrict__ GL) {
    int bid = blockIdx.x;
    int rp = bid & 63;
    int cp = bid >> 6;              // 0..339
    int c0 = cp * 2;
    __shared__ float wsh[36];
    int tid = threadIdx.x;
    if (tid < 36) {
        int ch = tid / 9, wi = tid % 9;
        int gch = c0 + (ch & 1) + ((ch >= 2) ? HID : 0);
        wsh[tid] = w9[gch * 9 + wi];
    }
    __syncthreads();
    int wq = tid & 127;
    int h = rp * 2 + (tid >> 7);
    const float* s1a = in + (size_t)c0 * NPIX;
    const float* s1b = s1a + NPIX;
    const float* s2a = in + (size_t)(c0 + HID) * NPIX;
    const float* s2b = s2a + NPIX;
    float a1a = bias[c0], a1b = bias[c0 + 1];
    float a2a = bias[c0 + HID], a2b = bias[c0 + 1 + HID];
    #pragma unroll
    for (int dy = -1; dy <= 1; ++dy) {
        int hh = h + dy;
        if (hh < 0 || hh > 127) continue;
        #pragma unroll
        for (int dx = -1; dx <= 1; ++dx) {
            int ww = wq + dx;
            if (ww < 0 || ww > 127) continue;
            int o = hh * 128 + ww;
            int wi = (dy + 1) * 3 + (dx + 1);
            a1a += wsh[wi] * s1a[o];
            a1b += wsh[9 + wi] * s1b[o];
            a2a += wsh[18 + wi] * s2a[o];
            a2b += wsh[27 + wi] * s2b[o];
        }
    }
    float g0 = 0.5f * a2a * (1.0f + erff(a2a * 0.70710678118654752f));
    float g1 = 0.5f * a2b * (1.0f + erff(a2b * 0.70710678118654752f));
    float o0 = a1a * g0, o1 = a1b * g1;
    ushort h0, l0, h1, l1; bf_split(o0, h0, l0); bf_split(o1, h1, l1);
    size_t w = (size_t)cp * NPIX + h * 128 + wq;
    GH[w] = (uint)h0 | ((uint)h1 << 16);
    GL[w] = (uint)l0 | ((uint)l1 << 16);
}

extern "C" void kernel_launch(void* const* d_in, const int* in_sizes, int n_in,
                              void* d_out, int out_size, void* d_ws, size_t ws_size,
                              hipStream_t stream) {
    const float* x        = (const float*)d_in[0];
    const float* n1w      = (const float*)d_in[1];
    const float* n1b      = (const float*)d_in[2];
    const float* temp     = (const float*)d_in[3];
    const float* qkv_w    = (const float*)d_in[4];
    const float* qkv_b    = (const float*)d_in[5];
    const float* qkv_dw_w = (const float*)d_in[6];
    const float* qkv_dw_b = (const float*)d_in[7];
    const float* po_w     = (const float*)d_in[8];
    const float* po_b     = (const float*)d_in[9];
    const float* n2w      = (const float*)d_in[10];
    const float* n2b      = (const float*)d_in[11];
    const float* pin_w    = (const float*)d_in[12];
    const float* pin_b    = (const float*)d_in[13];
    const float* dw_w     = (const float*)d_in[14];
    const float* dw_b     = (const float*)d_in[15];
    const float* pout_w   = (const float*)d_in[16];
    const float* pout_b   = (const float*)d_in[17];
    float* out = (float*)d_out;

    // ---- workspace arena (~184 MB) ----
    char* ws = (char*)d_ws;
    float* R0 = (float*)ws;                       // qkv fp32: 768*16384*4 = 50331648 B
    char*  R1c = ws + 50331648;                   // multi-use region, 50331648 B
    float* R1 = (float*)R1c;                      // dwconv out fp32
    float* R2 = (float*)(ws + 100663296);         // pin out fp32: 1360*16384*4 = 89128960 B
    char*  wb = ws + 189792256;
    ushort* WqkvH = (ushort*)wb;
    ushort* WqkvL = WqkvH + 196608;
    ushort* WpoH  = WqkvL + 196608;
    ushort* WpoL  = WpoH + 65536;
    ushort* WpinH = WpoL + 65536;
    ushort* WpinL = WpinH + 348160;
    ushort* WpoutH = WpinL + 348160;
    ushort* WpoutL = WpoutH + 174080;
    float* G     = (float*)(wb + 3137536);
    float* ssq   = G + 8192;
    float* ssk   = ssq + 256;
    float* attnA = ssk + 256;
    // aliased activation bf16 buffers inside R1 region (lifetimes are disjoint):
    uint* XHp = (uint*)R1c;                       // 128*16384 u32 = 8 MB
    uint* XLp = XHp + 2097152;
    uint* VHp = (uint*)R1c;                       // reuses q-section after gram
    uint* VLp = XLp;
    uint* GHp = (uint*)R1c;                       // 340*16384 u32 = 22.3 MB
    uint* GLp = GHp + 5570560;

    convert_weights<<<3064, 256, 0, stream>>>(qkv_w, po_w, pin_w, pout_w,
                                              WqkvH, WqkvL, WpoH, WpoL,
                                              WpinH, WpinL, WpoutH, WpoutL);

    for (int b = 0; b < BATCH; ++b) {
        const float* xb = x + (size_t)b * DIM * NPIX;
        float* outb = out + (size_t)b * DIM * NPIX;

        // ---- attention branch ----
        ln_fused<<<256, 256, 0, stream>>>(xb, n1w, n1b, XHp, XLp);
        gemm_mfma<false><<<dim3(128, 6), 256, 0, stream>>>(
            WqkvH, WqkvL, XHp, XLp, qkv_b, nullptr, R0, CHQKV, DIM, 8);
        zero_kernel<<<34, 256, 0, stream>>>(G, 8704);   // G, ssq, ssk contiguous
        dwconv_sumsq<<<CHQKV * 64, 256, 0, stream>>>(R0, qkv_dw_w, qkv_dw_b, R1, ssq, ssk);
        gram_kernel<<<dim3(8, 32), 256, 0, stream>>>(R1, G);
        attn_softmax<<<8, 1024, 0, stream>>>(G, ssq, ssk, temp, attnA);
        pv_kernel<<<dim3(8, 64), 256, 0, stream>>>(attnA, R1, VHp, VLp);
        gemm_mfma<true><<<dim3(128, 2), 256, 0, stream>>>(
            WpoH, WpoL, VHp, VLp, po_b, xb, outb, DIM, DIM, 8);

        // ---- FFN branch ----
        ln_fused<<<256, 256, 0, stream>>>(outb, n2w, n2b, XHp, XLp);
        gemm_mfma<false><<<dim3(128, 11), 256, 0, stream>>>(
            WpinH, WpinL, XHp, XLp, pin_b, nullptr, R2, HID2, DIM, 8);
        dwgate<<<340 * 64, 256, 0, stream>>>(R2, dw_w, dw_b, GHp, GLp);
        gemm_mfma<true><<<dim3(128, 2), 256, 0, stream>>>(
            WpoutH, WpoutL, GHp, GLp, pout_b, outb, outb, DIM, HID, 22);
    }
}

// Round 4
// 1549.910 us; speedup vs baseline: 1.8429x; 1.3232x over previous
//
#include <hip/hip_runtime.h>
#include <hip/hip_bf16.h>

#define NPIX 16384   // 128*128
#define BATCH 4
#define DIM 256
#define HEADS 8
#define HD 32
#define CHQKV 768
#define HID 680
#define HID2 1360

typedef __attribute__((ext_vector_type(8))) short short8v;
typedef __attribute__((ext_vector_type(4))) float float4v;

__device__ __forceinline__ ushort bf_hi(float v) {
    unsigned u = __float_as_uint(v);
    u += 0x7fffu + ((u >> 16) & 1u);          // RNE to bf16
    return (ushort)(u >> 16);
}
__device__ __forceinline__ float bf_tof(ushort h) {
    return __uint_as_float(((unsigned)h) << 16);
}
__device__ __forceinline__ void bf_split(float v, ushort &h, ushort &l) {
    h = bf_hi(v);
    l = bf_hi(v - bf_tof(h));
}

__global__ void zero_kernel(float* __restrict__ p, int n) {
    int i = blockIdx.x * blockDim.x + threadIdx.x;
    if (i < n) p[i] = 0.f;
}

// ---- one-time: split all 4 weight matrices into bf16 hi/lo planes ([m][k] layout) ----
__global__ void convert_weights(const float* __restrict__ qkv_w, const float* __restrict__ po_w,
                                const float* __restrict__ pin_w, const float* __restrict__ pout_w,
                                ushort* __restrict__ qH, ushort* __restrict__ qL,
                                ushort* __restrict__ oH, ushort* __restrict__ oL,
                                ushort* __restrict__ iH, ushort* __restrict__ iL,
                                ushort* __restrict__ uH, ushort* __restrict__ uL) {
    int i = blockIdx.x * 256 + threadIdx.x;
    const float* s; ushort *dh, *dl; int off;
    if (i < 196608)      { s = qkv_w;  dh = qH; dl = qL; off = i; }
    else if (i < 262144) { s = po_w;   dh = oH; dl = oL; off = i - 196608; }
    else if (i < 610304) { s = pin_w;  dh = iH; dl = iL; off = i - 262144; }
    else if (i < 784384) { s = pout_w; dh = uH; dl = uL; off = i - 610304; }
    else return;
    ushort h, l; bf_split(s[off], h, l);
    dh[off] = h; dl[off] = l;
}

// ---- fused LN stats + apply, writing k-pair-interleaved bf16 hi/lo planes ----
__global__ void ln_fused(const float* __restrict__ x, const float* __restrict__ lw,
                         const float* __restrict__ lb, uint* __restrict__ XH,
                         uint* __restrict__ XL) {
    __shared__ float Ss[256], Ss2[256], muS[64], rsS[64], wS[256], bS[256];
    int t = threadIdx.x, px = t & 63, cg = t >> 6, c0 = cg * 64;
    int p = blockIdx.x * 64 + px;
    wS[t] = lw[t]; bS[t] = lb[t];
    float v[64]; float s = 0.f, s2 = 0.f;
    #pragma unroll
    for (int j = 0; j < 64; ++j) {
        v[j] = x[(size_t)(c0 + j) * NPIX + p];
        s += v[j]; s2 += v[j] * v[j];
    }
    Ss[t] = s; Ss2[t] = s2;
    __syncthreads();
    if (t < 64) {
        float ts = Ss[t] + Ss[t + 64] + Ss[t + 128] + Ss[t + 192];
        float t2 = Ss2[t] + Ss2[t + 64] + Ss2[t + 128] + Ss2[t + 192];
        float m = ts * (1.0f / DIM);
        float var = t2 * (1.0f / DIM) - m * m;
        muS[t] = m; rsS[t] = rsqrtf(var + 1e-5f);
    }
    __syncthreads();
    float m = muS[px], r = rsS[px];
    #pragma unroll
    for (int j = 0; j < 64; j += 2) {
        float a = (v[j] - m) * r * wS[c0 + j] + bS[c0 + j];
        float b2 = (v[j + 1] - m) * r * wS[c0 + j + 1] + bS[c0 + j + 1];
        ushort h0, l0, h1, l1; bf_split(a, h0, l0); bf_split(b2, h1, l1);
        size_t w = (size_t)((c0 + j) >> 1) * NPIX + p;
        XH[w] = (uint)h0 | ((uint)h1 << 16);
        XL[w] = (uint)l0 | ((uint)l1 << 16);
    }
}

// ---- MFMA GEMM: Out(M,NPIX) = W(M,K) @ X(K,NPIX), 3-term bf16 hi/lo ----
template <bool RES>
__global__ void gemm_mfma(const ushort* __restrict__ WH, const ushort* __restrict__ WL,
                          const uint* __restrict__ BpH, const uint* __restrict__ BpL,
                          const float* __restrict__ bias, const float* __restrict__ res,
                          float* __restrict__ Out, int M, int K, int ksteps) {
    __shared__ uint BhL[128 * 20];
    __shared__ uint BlL[128 * 20];
    __shared__ float biasS[128];
    const int N = NPIX;
    int tid = threadIdx.x;
    int m0 = blockIdx.y * 128;
    int n0 = blockIdx.x * 128;
    int l = tid & 63;
    int wid = tid >> 6;
    int wr = wid >> 1, wc = wid & 1;
    int lr = l & 15, lk = l >> 4;
    int kp = tid & 15;
    int nn8 = (tid >> 4) * 8;

    if (tid < 128) biasS[tid] = (m0 + tid < M) ? bias[m0 + tid] : 0.f;

    float4v acc[4][4];
    #pragma unroll
    for (int i = 0; i < 4; ++i)
        #pragma unroll
        for (int j = 0; j < 4; ++j) acc[i][j] = (float4v)0.f;

    const int Kh = K >> 1;
    for (int ks = 0; ks < ksteps; ++ks) {
        int k0 = ks * 32;
        int kpg = (k0 >> 1) + kp;
        bool kin = kpg < Kh;
        int kpc = kin ? kpg : (Kh - 1);
        const uint* ph = &BpH[(size_t)kpc * N + n0 + nn8];
        const uint* pl = &BpL[(size_t)kpc * N + n0 + nn8];
        uint4 h0 = *(const uint4*)ph;
        uint4 h1 = *(const uint4*)(ph + 4);
        uint4 g0 = *(const uint4*)pl;
        uint4 g1 = *(const uint4*)(pl + 4);
        if (!kin) {
            h0 = make_uint4(0, 0, 0, 0); h1 = h0; g0 = h0; g1 = h0;
        }
        __syncthreads();
        int r0 = nn8 * 20 + kp;
        BhL[r0      ] = h0.x; BhL[r0 + 20] = h0.y; BhL[r0 + 40] = h0.z; BhL[r0 + 60] = h0.w;
        BhL[r0 + 80 ] = h1.x; BhL[r0 +100] = h1.y; BhL[r0 +120] = h1.z; BhL[r0 +140] = h1.w;
        BlL[r0      ] = g0.x; BlL[r0 + 20] = g0.y; BlL[r0 + 40] = g0.z; BlL[r0 + 60] = g0.w;
        BlL[r0 + 80 ] = g1.x; BlL[r0 +100] = g1.y; BlL[r0 +120] = g1.z; BlL[r0 +140] = g1.w;
        __syncthreads();

        short8v ah[4], al[4], bh[4], bl[4];
        int kk = k0 + lk * 8;
        bool kok = (kk + 7) < K;
        int kc = kok ? kk : 0;
        #pragma unroll
        for (int mi = 0; mi < 4; ++mi) {
            int arow = m0 + wr * 64 + mi * 16 + lr;
            bool ok = (arow < M) && kok;
            int arc = arow < M ? arow : (M - 1);
            short8v th = *(const short8v*)&WH[(size_t)arc * K + kc];
            short8v tl = *(const short8v*)&WL[(size_t)arc * K + kc];
            short8v z = (short8v)0;
            ah[mi] = ok ? th : z;
            al[mi] = ok ? tl : z;
        }
        #pragma unroll
        for (int ni = 0; ni < 4; ++ni) {
            int brow = wc * 64 + ni * 16 + lr;
            bh[ni] = *(const short8v*)&BhL[brow * 20 + lk * 4];
            bl[ni] = *(const short8v*)&BlL[brow * 20 + lk * 4];
        }
        #pragma unroll
        for (int mi = 0; mi < 4; ++mi)
            #pragma unroll
            for (int ni = 0; ni < 4; ++ni) {
                acc[mi][ni] = __builtin_amdgcn_mfma_f32_16x16x32_bf16(ah[mi], bh[ni], acc[mi][ni], 0, 0, 0);
                acc[mi][ni] = __builtin_amdgcn_mfma_f32_16x16x32_bf16(ah[mi], bl[ni], acc[mi][ni], 0, 0, 0);
                acc[mi][ni] = __builtin_amdgcn_mfma_f32_16x16x32_bf16(al[mi], bh[ni], acc[mi][ni], 0, 0, 0);
            }
    }

    int lr4 = lk * 4;
    #pragma unroll
    for (int mi = 0; mi < 4; ++mi) {
        #pragma unroll
        for (int ni = 0; ni < 4; ++ni) {
            int rloc = wr * 64 + mi * 16 + lr4;
            int col = n0 + wc * 64 + ni * 16 + lr;
            #pragma unroll
            for (int r = 0; r < 4; ++r) {
                int row = m0 + rloc + r;
                if (row < M) {
                    float v = acc[mi][ni][r] + biasS[rloc + r];
                    size_t o = (size_t)row * N + col;
                    if (RES) v += res[o];
                    Out[o] = v;
                }
            }
        }
    }
}

// ---- depthwise 3x3 (SAME) tiled in LDS, fused sum-of-squares for q,k ----
__global__ void dwconv_sumsq(const float* __restrict__ in, const float* __restrict__ w9,
                             const float* __restrict__ bias, float* __restrict__ out,
                             float* __restrict__ ssq, float* __restrict__ ssk) {
    // grid = 768*4: ch = bid>>2, rt = bid&3; tile 32 rows x 128 cols
    __shared__ float T[34][132];
    __shared__ float red[256];
    int bid = blockIdx.x;
    int ch = bid >> 2, rt = bid & 3;
    int g0 = rt * 32;
    int t = threadIdx.x;
    const float* src = in + (size_t)ch * NPIX;
    int c4 = (t & 31) * 4;
    for (int rr = t >> 5; rr < 34; rr += 8) {
        int grow = g0 - 1 + rr;
        float4 v = make_float4(0.f, 0.f, 0.f, 0.f);
        if (grow >= 0 && grow < 128) v = *(const float4*)&src[grow * 128 + c4];
        *(float4*)&T[rr][c4 + 1] = v;
    }
    if (t < 34) { T[t][0] = 0.f; T[t][129] = 0.f; }
    float wgt[9];
    #pragma unroll
    for (int i = 0; i < 9; ++i) wgt[i] = w9[ch * 9 + i];
    float bi = bias[ch];
    __syncthreads();
    int w = t & 127;
    int jb = (t >> 7) * 16;
    float a0 = T[jb][w], a1 = T[jb][w + 1], a2 = T[jb][w + 2];
    float b0 = T[jb + 1][w], b1 = T[jb + 1][w + 1], b2 = T[jb + 1][w + 2];
    float sq = 0.f;
    float* dst = out + (size_t)ch * NPIX + (g0 + jb) * 128 + w;
    #pragma unroll
    for (int i = 0; i < 16; ++i) {
        float c0 = T[jb + i + 2][w], c1 = T[jb + i + 2][w + 1], c2 = T[jb + i + 2][w + 2];
        float acc = bi + wgt[0] * a0 + wgt[1] * a1 + wgt[2] * a2
                       + wgt[3] * b0 + wgt[4] * b1 + wgt[5] * b2
                       + wgt[6] * c0 + wgt[7] * c1 + wgt[8] * c2;
        dst[i * 128] = acc;
        sq += acc * acc;
        a0 = b0; a1 = b1; a2 = b2; b0 = c0; b1 = c1; b2 = c2;
    }
    if (ch < 512) {
        red[t] = sq;
        __syncthreads();
        for (int st = 128; st > 0; st >>= 1) {
            if (t < st) red[t] += red[t + st];
            __syncthreads();
        }
        if (t == 0) {
            float* d2 = (ch < DIM) ? &ssq[ch] : &ssk[ch - DIM];
            atomicAdd(d2, red[0]);
        }
    }
}

// ---- Gram: G[h,c,d] = sum_n q[c,n]*k[d,n] ----
__global__ void gram_kernel(const float* __restrict__ qkv, float* __restrict__ G) {
    int hH = blockIdx.x;
    int n0 = blockIdx.y * 512;
    __shared__ float qs[32][68];
    __shared__ float ks[32][68];
    int tid = threadIdx.x;
    int c = tid >> 3;
    int lo = (tid & 7) * 8;
    int dbase = tid & 7;
    const float* qbase = qkv + ((size_t)hH * HD + c) * NPIX;
    const float* kbase = qbase + (size_t)DIM * NPIX;
    float acc[4] = {0.f, 0.f, 0.f, 0.f};
    for (int t0 = 0; t0 < 512; t0 += 64) {
        __syncthreads();
        *(float4*)&qs[c][lo]     = *(const float4*)&qbase[n0 + t0 + lo];
        *(float4*)&qs[c][lo + 4] = *(const float4*)&qbase[n0 + t0 + lo + 4];
        *(float4*)&ks[c][lo]     = *(const float4*)&kbase[n0 + t0 + lo];
        *(float4*)&ks[c][lo + 4] = *(const float4*)&kbase[n0 + t0 + lo + 4];
        __syncthreads();
        for (int t = 0; t < 64; ++t) {
            float qv = qs[c][t];
            #pragma unroll
            for (int j = 0; j < 4; ++j) acc[j] += qv * ks[dbase + 8 * j][t];
        }
    }
    float* Gb = G + hH * 1024 + c * 32;
    #pragma unroll
    for (int j = 0; j < 4; ++j) atomicAdd(&Gb[dbase + 8 * j], acc[j]);
}

// ---- softmax over d with l2-norm scaling and temperature ----
__global__ void attn_softmax(const float* __restrict__ G, const float* __restrict__ ssq,
                             const float* __restrict__ ssk, const float* __restrict__ temp,
                             float* __restrict__ A) {
    int hH = blockIdx.x;
    int tid = threadIdx.x;
    int c = tid >> 5, d = tid & 31;
    float nq = fmaxf(sqrtf(ssq[hH * HD + c]), 1e-12f);
    float nk = fmaxf(sqrtf(ssk[hH * HD + d]), 1e-12f);
    float v = G[hH * 1024 + c * 32 + d] / (nq * nk) * temp[hH];
    float m = v;
    #pragma unroll
    for (int s = 1; s < 32; s <<= 1) m = fmaxf(m, __shfl_xor(m, s, 32));
    float e = expf(v - m);
    float ssum = e;
    #pragma unroll
    for (int s = 1; s < 32; s <<= 1) ssum += __shfl_xor(ssum, s, 32);
    A[hH * 1024 + c * 32 + d] = e / ssum;
}

// ---- PV: writes paired bf16 hi/lo ----
__global__ void pv_kernel(const float* __restrict__ A, const float* __restrict__ qkv,
                          uint* __restrict__ VH, uint* __restrict__ VL) {
    int hH = blockIdx.x;
    int n = blockIdx.y * 256 + threadIdx.x;
    __shared__ float As[1024];
    for (int i = threadIdx.x; i < 1024; i += 256) As[i] = A[hH * 1024 + i];
    __syncthreads();
    const float* vbase = qkv + ((size_t)(512 + hH * HD)) * NPIX + n;
    float vv[32];
    #pragma unroll
    for (int d = 0; d < 32; ++d) vv[d] = vbase[(size_t)d * NPIX];
    #pragma unroll
    for (int cc = 0; cc < 32; cc += 2) {
        float a0 = 0.f, a1 = 0.f;
        #pragma unroll
        for (int d = 0; d < 32; ++d) {
            a0 += As[cc * 32 + d] * vv[d];
            a1 += As[cc * 32 + 32 + d] * vv[d];
        }
        ushort h0, l0, h1, l1; bf_split(a0, h0, l0); bf_split(a1, h1, l1);
        size_t w = (size_t)((hH * HD + cc) >> 1) * NPIX + n;
        VH[w] = (uint)h0 | ((uint)h1 << 16);
        VL[w] = (uint)l0 | ((uint)l1 << 16);
    }
}

// ---- FFN depthwise 3x3 + gelu gating, tiled in LDS, paired bf16 out ----
__global__ void dwgate(const float* __restrict__ in, const float* __restrict__ w9,
                       const float* __restrict__ bias, uint* __restrict__ GH,
                       uint* __restrict__ GL) {
    // grid = 340*8: cp = bid>>3, rt = bid&7; tile 16 rows x 128 cols, 4 planes
    __shared__ float T[4][18][132];
    int bid = blockIdx.x;
    int cp = bid >> 3, rt = bid & 7;
    int c0 = cp * 2;
    int g0 = rt * 16;
    int t = threadIdx.x;
    for (int idx = t; idx < 4 * 18 * 32; idx += 256) {
        int pl = idx / 576;
        int rem = idx - pl * 576;
        int rr = rem >> 5;
        int cc4 = (rem & 31) * 4;
        int ch = c0 + (pl & 1) + (pl >> 1) * HID;
        int grow = g0 - 1 + rr;
        float4 v = make_float4(0.f, 0.f, 0.f, 0.f);
        if (grow >= 0 && grow < 128)
            v = *(const float4*)&in[(size_t)ch * NPIX + grow * 128 + cc4];
        *(float4*)&T[pl][rr][cc4 + 1] = v;
    }
    if (t < 72) {
        int pl = t / 18, rr = t % 18;
        T[pl][rr][0] = 0.f; T[pl][rr][129] = 0.f;
    }
    float wg[4][9]; float bs[4];
    #pragma unroll
    for (int p = 0; p < 4; ++p) {
        int ch = c0 + (p & 1) + (p >> 1) * HID;
        bs[p] = bias[ch];
        #pragma unroll
        for (int i = 0; i < 9; ++i) wg[p][i] = w9[ch * 9 + i];
    }
    __syncthreads();
    int w = t & 127;
    int jb = (t >> 7) * 8;
    float A[4][3], B[4][3];
    #pragma unroll
    for (int p = 0; p < 4; ++p) {
        A[p][0] = T[p][jb][w];     A[p][1] = T[p][jb][w + 1];     A[p][2] = T[p][jb][w + 2];
        B[p][0] = T[p][jb + 1][w]; B[p][1] = T[p][jb + 1][w + 1]; B[p][2] = T[p][jb + 1][w + 2];
    }
    size_t wbase = (size_t)cp * NPIX + (g0 + jb) * 128 + w;
    #pragma unroll
    for (int i = 0; i < 8; ++i) {
        float o[4];
        #pragma unroll
        for (int p = 0; p < 4; ++p) {
            float cA = T[p][jb + i + 2][w], cB = T[p][jb + i + 2][w + 1], cC = T[p][jb + i + 2][w + 2];
            o[p] = bs[p] + wg[p][0] * A[p][0] + wg[p][1] * A[p][1] + wg[p][2] * A[p][2]
                         + wg[p][3] * B[p][0] + wg[p][4] * B[p][1] + wg[p][5] * B[p][2]
                         + wg[p][6] * cA + wg[p][7] * cB + wg[p][8] * cC;
            A[p][0] = B[p][0]; A[p][1] = B[p][1]; A[p][2] = B[p][2];
            B[p][0] = cA; B[p][1] = cB; B[p][2] = cC;
        }
        float g0f = 0.5f * o[2] * (1.0f + erff(o[2] * 0.70710678118654752f));
        float g1f = 0.5f * o[3] * (1.0f + erff(o[3] * 0.70710678118654752f));
        float r0 = o[0] * g0f, r1 = o[1] * g1f;
        ushort h0, l0, h1, l1; bf_split(r0, h0, l0); bf_split(r1, h1, l1);
        GH[wbase + i * 128] = (uint)h0 | ((uint)h1 << 16);
        GL[wbase + i * 128] = (uint)l0 | ((uint)l1 << 16);
    }
}

extern "C" void kernel_launch(void* const* d_in, const int* in_sizes, int n_in,
                              void* d_out, int out_size, void* d_ws, size_t ws_size,
                              hipStream_t stream) {
    const float* x        = (const float*)d_in[0];
    const float* n1w      = (const float*)d_in[1];
    const float* n1b      = (const float*)d_in[2];
    const float* temp     = (const float*)d_in[3];
    const float* qkv_w    = (const float*)d_in[4];
    const float* qkv_b    = (const float*)d_in[5];
    const float* qkv_dw_w = (const float*)d_in[6];
    const float* qkv_dw_b = (const float*)d_in[7];
    const float* po_w     = (const float*)d_in[8];
    const float* po_b     = (const float*)d_in[9];
    const float* n2w      = (const float*)d_in[10];
    const float* n2b      = (const float*)d_in[11];
    const float* pin_w    = (const float*)d_in[12];
    const float* pin_b    = (const float*)d_in[13];
    const float* dw_w     = (const float*)d_in[14];
    const float* dw_b     = (const float*)d_in[15];
    const float* pout_w   = (const float*)d_in[16];
    const float* pout_b   = (const float*)d_in[17];
    float* out = (float*)d_out;

    // ---- workspace arena (~184 MB) ----
    char* ws = (char*)d_ws;
    float* R0 = (float*)ws;                       // qkv fp32: 50331648 B
    char*  R1c = ws + 50331648;                   // multi-use region, 50331648 B
    float* R1 = (float*)R1c;                      // dwconv out fp32
    float* R2 = (float*)(ws + 100663296);         // pin out fp32: 89128960 B
    char*  wb = ws + 189792256;
    ushort* WqkvH = (ushort*)wb;
    ushort* WqkvL = WqkvH + 196608;
    ushort* WpoH  = WqkvL + 196608;
    ushort* WpoL  = WpoH + 65536;
    ushort* WpinH = WpoL + 65536;
    ushort* WpinL = WpinH + 348160;
    ushort* WpoutH = WpinL + 348160;
    ushort* WpoutL = WpoutH + 174080;
    float* G     = (float*)(wb + 3137536);
    float* ssq   = G + 8192;
    float* ssk   = ssq + 256;
    float* attnA = ssk + 256;
    uint* XHp = (uint*)R1c;
    uint* XLp = XHp + 2097152;
    uint* VHp = (uint*)R1c;
    uint* VLp = XLp;
    uint* GHp = (uint*)R1c;
    uint* GLp = GHp + 5570560;

    convert_weights<<<3064, 256, 0, stream>>>(qkv_w, po_w, pin_w, pout_w,
                                              WqkvH, WqkvL, WpoH, WpoL,
                                              WpinH, WpinL, WpoutH, WpoutL);

    for (int b = 0; b < BATCH; ++b) {
        const float* xb = x + (size_t)b * DIM * NPIX;
        float* outb = out + (size_t)b * DIM * NPIX;

        // ---- attention branch ----
        ln_fused<<<256, 256, 0, stream>>>(xb, n1w, n1b, XHp, XLp);
        gemm_mfma<false><<<dim3(128, 6), 256, 0, stream>>>(
            WqkvH, WqkvL, XHp, XLp, qkv_b, nullptr, R0, CHQKV, DIM, 8);
        zero_kernel<<<34, 256, 0, stream>>>(G, 8704);
        dwconv_sumsq<<<CHQKV * 4, 256, 0, stream>>>(R0, qkv_dw_w, qkv_dw_b, R1, ssq, ssk);
        gram_kernel<<<dim3(8, 32), 256, 0, stream>>>(R1, G);
        attn_softmax<<<8, 1024, 0, stream>>>(G, ssq, ssk, temp, attnA);
        pv_kernel<<<dim3(8, 64), 256, 0, stream>>>(attnA, R1, VHp, VLp);
        gemm_mfma<true><<<dim3(128, 2), 256, 0, stream>>>(
            WpoH, WpoL, VHp, VLp, po_b, xb, outb, DIM, DIM, 8);

        // ---- FFN branch ----
        ln_fused<<<256, 256, 0, stream>>>(outb, n2w, n2b, XHp, XLp);
        gemm_mfma<false><<<dim3(128, 11), 256, 0, stream>>>(
            WpinH, WpinL, XHp, XLp, pin_b, nullptr, R2, HID2, DIM, 8);
        dwgate<<<340 * 8, 256, 0, stream>>>(R2, dw_w, dw_b, GHp, GLp);
        gemm_mfma<true><<<dim3(128, 2), 256, 0, stream>>>(
            WpoutH, WpoutL, GHp, GLp, pout_b, outb, outb, DIM, HID, 22);
    }
}